// Round 13
// baseline (994.434 us; speedup 1.0000x reference)
//
#include <hip/hip_runtime.h>
#include <hip/hip_bf16.h>
#include <stdint.h>

#define Bb 4
#define Ss 8192
#define Hh 2048
#define NHh 16
#define DHh 128
#define DFFf 8192
#define KS 1024
#define NTOK 4096

typedef unsigned short u16;
typedef __bf16 bf16x8 __attribute__((ext_vector_type(8)));
typedef float f32x4 __attribute__((ext_vector_type(4)));

union B8 { uint4 u; bf16x8 v; u16 s[8]; };

__device__ __forceinline__ float b2f(u16 x) { return __uint_as_float(((unsigned)x) << 16); }
__device__ __forceinline__ u16 f2b(float x) {
  __hip_bfloat16 h = __float2bfloat16(x);
  return *reinterpret_cast<u16*>(&h);
}

__device__ __forceinline__ void gll16(const void* g, void* l) {
  __builtin_amdgcn_global_load_lds((const __attribute__((address_space(1))) void*)g,
                                   (__attribute__((address_space(3))) void*)l, 16, 0, 0);
}

__device__ __forceinline__ int swz16(int r, int cg) {
  int u = ((r & 1) << 2) | cg;
  return ((r >> 1) << 3) | (u ^ ((r >> 1) & 7));
}

// ---------------- full hidden -> out copy (536 MB round trip, compute-kernel BW) ----------------
__global__ __launch_bounds__(256) void copy_hid(const uint4* __restrict__ src,
                                                uint4* __restrict__ dst) {
  // 4*8192*2048 floats = 16,777,216 uint4s; 2048 blocks x 256 thr x 32 each
  size_t base = (size_t)blockIdx.x * 256 + threadIdx.x;
#pragma unroll
  for (int j = 0; j < 32; ++j) {
    size_t i = base + (size_t)j * 524288;
    dst[i] = src[i];
  }
}

// ---------------- top-k index scan ----------------
__global__ void topk_prep(const void* maskp, const int* __restrict__ posids,
                          const float* __restrict__ scores,
                          int* __restrict__ idx, int* __restrict__ posg,
                          float* __restrict__ scalev) {
  int b = blockIdx.x;
  int tid = threadIdx.x, lane = tid & 63, wv = tid >> 6;
  __shared__ int wsum[4];
  __shared__ int base;
  __shared__ int mode;
  __shared__ int detCnt;
  if (tid == 0) { base = 0; detCnt = 0; }
  __syncthreads();
  {
    const unsigned char* mb = (const unsigned char*)maskp;
    int c = 0;
    for (int s = tid; s < 8192; s += 256) c += (mb[s] != 0);
    atomicAdd(&detCnt, c);
  }
  __syncthreads();
  if (tid == 0) mode = (detCnt == KS) ? 1 : 0;
  __syncthreads();
  const unsigned char* mb = (const unsigned char*)maskp;
  const int* mi = (const int*)maskp;
  for (int s0 = 0; s0 < Ss; s0 += 256) {
    int s = s0 + tid;
    int pred = mode ? (mb[(size_t)b * Ss + s] != 0) : (mi[(size_t)b * Ss + s] != 0);
    unsigned long long bal = __ballot(pred);
    int lp = __popcll(bal & ((1ull << lane) - 1ull));
    int wtot = __popcll(bal);
    if (lane == 0) wsum[wv] = wtot;
    __syncthreads();
    int woff = 0;
    for (int w = 0; w < wv; ++w) woff += wsum[w];
    int tot = wsum[0] + wsum[1] + wsum[2] + wsum[3];
    int p = base + woff + lp;
    if (pred && p < KS) {
      idx[b * KS + p] = s;
      posg[b * KS + p] = posids[(size_t)b * Ss + s];
    }
    __syncthreads();
    if (tid == 0) base += tot;
    __syncthreads();
  }
  if (b == 0 && tid < Bb) scalev[tid] = 0.5f * 1.0f + (scores[tid] - 0.5f) * 1.0f;
}

// ---------------- weight transpose fp32 -> bf16 (64x32 tile, vectorized stores) ----------------
template <int MODE>
__global__ __launch_bounds__(256) void transpose_w(const float* __restrict__ in,
                                                   u16* __restrict__ out, int R, int C) {
  __shared__ float tile[64][33];
  int t = threadIdx.x;
  int c0 = blockIdx.x * 32, r0 = blockIdx.y * 64;
  int tx = t & 31, ty = t >> 5;
#pragma unroll
  for (int j = 0; j < 8; ++j)
    tile[j * 8 + ty][tx] = in[(size_t)(r0 + j * 8 + ty) * C + c0 + tx];
  __syncthreads();
  int c = t >> 3, g = t & 7;
  int cc = c0 + c;
  size_t row = (MODE == 0) ? (size_t)cc
                           : (size_t)((cc >> 5) << 6) + (cc & 31) + (MODE == 2 ? 32 : 0);
  B8 pk;
#pragma unroll
  for (int k = 0; k < 8; ++k) pk.s[k] = f2b(tile[g * 8 + k][c]);
  *(uint4*)&out[row * R + r0 + g * 8] = pk.u;
}

// ---------------- RMSNorm ----------------
template <int GATHER>
__global__ __launch_bounds__(256) void rmsnorm_k(const float* __restrict__ src0,
                                                 const int* __restrict__ idx,
                                                 const float* __restrict__ w,
                                                 u16* __restrict__ out) {
  int t = blockIdx.x;
  const float* src;
  if (GATHER) { int b = t >> 10; src = src0 + ((size_t)b * Ss + idx[t]) * Hh; }
  else src = src0 + (size_t)t * Hh;
  int tid = threadIdx.x, lane = tid & 63, wv = tid >> 6;
  float4 x0 = *(const float4*)(src + tid * 8);
  float4 x1 = *(const float4*)(src + tid * 8 + 4);
  float ss = x0.x * x0.x + x0.y * x0.y + x0.z * x0.z + x0.w * x0.w +
             x1.x * x1.x + x1.y * x1.y + x1.z * x1.z + x1.w * x1.w;
  for (int o = 32; o; o >>= 1) ss += __shfl_down(ss, o);
  __shared__ float wred[4];
  if (lane == 0) wred[wv] = ss;
  __syncthreads();
  float tot = wred[0] + wred[1] + wred[2] + wred[3];
  float r = rsqrtf(tot * (1.0f / Hh) + 1e-5f);
  const float* wp = w + tid * 8;
  u16* op = out + (size_t)t * Hh + tid * 8;
  float xs[8] = {x0.x, x0.y, x0.z, x0.w, x1.x, x1.y, x1.z, x1.w};
#pragma unroll
  for (int j = 0; j < 8; ++j) op[j] = f2b(xs[j] * r * wp[j]);
}

// ---------------- 256x256 8-phase bf16 GEMM, pair-unrolled (frozen K-loop) ----------------
template <int EPI>
__global__ __launch_bounds__(512, 2) void gemm256(
    const u16* __restrict__ A, const u16* __restrict__ Bt,
    int N, int Kd, int lda, int gm, int gw, int nb,
    u16* __restrict__ Cb,
    const float* __restrict__ hid, const int* __restrict__ idx,
    const float* __restrict__ hs2, const float* __restrict__ scalev,
    float* __restrict__ Cf) {
  __shared__ u16 lds[65536];
  int bid = blockIdx.x;
  int xcd = bid & 7;
  int i2 = bid >> 3;
  int bm = i2 / gw;
  int bn = xcd * gw + i2 % gw + nb;
  int m0 = bm * 256, n0 = bn * 256;
  int tid = threadIdx.x, lane = tid & 63, wv = tid >> 6;
  int wm = wv >> 2, wn = wv & 3;
  int NT = Kd >> 6;

  int P16 = wv * 64 + lane;
  int blk = P16 >> 3, up = P16 & 7;
  int uu = up ^ (blk & 7);
  int r0 = blk * 2 + (uu >> 2), cg0 = uu & 3;
  const u16* srcA = A + (size_t)(m0 + r0) * lda + cg0 * 8;
  const u16* srcB = Bt + (size_t)(n0 + r0) * Kd + cg0 * 8;
  size_t rsA = (size_t)128 * lda, rsB = (size_t)128 * Kd;

  int offA = swz16(wm * 128 + (lane & 15), lane >> 4) * 8;
  int offB = 32768 + swz16(wn * 64 + (lane & 15), lane >> 4) * 8;
  u16* ldsw = &lds[wv * 512];

  f32x4 acc[8][4] = {};
  B8 aR[4], bR[4];

  gll16(srcB,      ldsw + 32768); gll16(srcB + rsB,      ldsw + 36864);
  gll16(srcA,      ldsw +     0); gll16(srcA + rsA,      ldsw +  4096);
  gll16(srcB + 32, ldsw + 40960); gll16(srcB + 32 + rsB, ldsw + 45056);
  gll16(srcA + 32, ldsw +  8192); gll16(srcA + 32 + rsA, ldsw + 12288);
  gll16(srcB + 64, ldsw + 49152); gll16(srcB + 64 + rsB, ldsw + 53248);
  gll16(srcA + 64, ldsw + 16384); gll16(srcA + 64 + rsA, ldsw + 20480);
  gll16(srcB + 96, ldsw + 57344); gll16(srcB + 96 + rsB, ldsw + 61440);
  asm volatile("s_waitcnt vmcnt(6)" ::: "memory");
  asm volatile("s_barrier" ::: "memory");

  const u16* stA = srcA + 64;
  const u16* stB = srcB + 64;

  auto phase = [&](int abase, int bbase, int mh) {
    if (mh == 0) {
#pragma unroll
      for (int nf = 0; nf < 4; ++nf) bR[nf].u = *(const uint4*)&lds[offB + bbase + nf * 512];
    }
#pragma unroll
    for (int i3 = 0; i3 < 4; ++i3)
      aR[i3].u = *(const uint4*)&lds[offA + abase + (i3 + 4 * mh) * 512];
  };
  auto mfma16 = [&](int mh) {
    asm volatile("s_barrier" ::: "memory");
    asm volatile("s_waitcnt lgkmcnt(0)" ::: "memory");
    __builtin_amdgcn_s_setprio(1);
#pragma unroll
    for (int nf = 0; nf < 4; ++nf)
#pragma unroll
      for (int i3 = 0; i3 < 4; ++i3)
        acc[mh * 4 + i3][nf] =
            __builtin_amdgcn_mfma_f32_16x16x32_bf16(aR[i3].v, bR[nf].v, acc[mh * 4 + i3][nf], 0, 0, 0);
    __builtin_amdgcn_s_setprio(0);
  };

  for (int ktp = 0; ktp < NT; ktp += 2) {
    bool sAll = (ktp < NT - 2);
    phase(0, 0, 0);
    { gll16(stA + 32, ldsw + 24576); gll16(stA + 32 + rsA, ldsw + 28672); }
    mfma16(0);
    asm volatile("s_barrier" ::: "memory");
    phase(0, 0, 1);
    if (sAll) { gll16(stB + 64, ldsw + 32768); gll16(stB + 64 + rsB, ldsw + 36864); }
    mfma16(1);
    asm volatile("s_barrier" ::: "memory");
    phase(8192, 8192, 0);
    if (sAll) { gll16(stA + 64, ldsw + 0); gll16(stA + 64 + rsA, ldsw + 4096); }
    mfma16(0);
    asm volatile("s_barrier" ::: "memory");
    phase(8192, 8192, 1);
    if (sAll) { gll16(stB + 96, ldsw + 40960); gll16(stB + 96 + rsB, ldsw + 45056); }
    mfma16(1);
    if (sAll) asm volatile("s_waitcnt vmcnt(6)" ::: "memory");
    else asm volatile("s_waitcnt vmcnt(0)" ::: "memory");
    asm volatile("s_barrier" ::: "memory");
    phase(16384, 16384, 0);
    if (sAll) { gll16(stA + 96, ldsw + 8192); gll16(stA + 96 + rsA, ldsw + 12288); }
    mfma16(0);
    asm volatile("s_barrier" ::: "memory");
    phase(16384, 16384, 1);
    if (sAll) { gll16(stB + 128, ldsw + 49152); gll16(stB + 128 + rsB, ldsw + 53248); }
    mfma16(1);
    asm volatile("s_barrier" ::: "memory");
    phase(24576, 24576, 0);
    if (sAll) { gll16(stA + 128, ldsw + 16384); gll16(stA + 128 + rsA, ldsw + 20480); }
    mfma16(0);
    asm volatile("s_barrier" ::: "memory");
    phase(24576, 24576, 1);
    if (sAll) { gll16(stB + 160, ldsw + 57344); gll16(stB + 160 + rsB, ldsw + 61440); }
    mfma16(1);
    if (sAll) asm volatile("s_waitcnt vmcnt(6)" ::: "memory");
    asm volatile("s_barrier" ::: "memory");
    stA += 128; stB += 128;
  }

  if (EPI == 4) {
    int gcol0 = ((n0 + wn * 64) >> 1) + (lane & 15);
#pragma unroll
    for (int mf = 0; mf < 8; ++mf) {
#pragma unroll
      for (int rr = 0; rr < 4; ++rr) {
        int row = m0 + wm * 128 + mf * 16 + (lane >> 4) * 4 + rr;
#pragma unroll
        for (int nf = 0; nf < 2; ++nf) {
          float g = acc[mf][nf][rr];
          float u = acc[mf][nf + 2][rr];
          Cb[(size_t)row * 8192 + gcol0 + nf * 16] = f2b(g / (1.0f + __expf(-g)) * u);
        }
      }
    }
    return;
  }

#pragma unroll
  for (int mf = 0; mf < 8; ++mf) {
#pragma unroll
    for (int rr = 0; rr < 4; ++rr) {
      int row = m0 + wm * 128 + mf * 16 + (lane >> 4) * 4 + rr;
#pragma unroll
      for (int nf = 0; nf < 4; ++nf) {
        int col = n0 + wn * 64 + nf * 16 + (lane & 15);
        float v = acc[mf][nf][rr];
        if (EPI == 0) {
          Cb[(size_t)row * N + col] = f2b(v);
        } else if (EPI == 1) {
          int b = row >> 10;
          Cf[(size_t)row * Hh + col] = hid[((size_t)b * Ss + idx[row]) * Hh + col] + v;
        } else {
          int b = row >> 10;
          Cf[((size_t)b * Ss + idx[row]) * Hh + col] = hs2[(size_t)row * Hh + col] + v * scalev[b];
        }
      }
    }
  }
}

// ---------------- 128x256 bf16 GEMM, 3-slot/36KB, pipelined ----------------
template <int EPI>
__global__ __launch_bounds__(512, 4) void gemm128(
    const u16* __restrict__ A, const u16* __restrict__ Bt,
    int N, int Kd, int lda, int gm, int gw, int r2d,
    u16* __restrict__ Cb,
    const float* __restrict__ hid, const int* __restrict__ idx,
    const float* __restrict__ hs2, const float* __restrict__ scalev,
    float* __restrict__ Cf, u16* __restrict__ vTout) {
  __shared__ u16 lds[36864];
  int bid = blockIdx.x;
  int xcd = bid & 7;
  int i2 = bid >> 3;
  int bm, bn;
  if (r2d) {
    int xr = xcd >> 1, xc = xcd & 1;
    bm = xr * 8 + (i2 & 7);
    bn = xc * 4 + (i2 >> 3);
  } else {
    bm = i2 / gw;
    bn = xcd * gw + i2 % gw;
  }
  int m0 = bm * 128, n0 = bn * 256;
  int tid = threadIdx.x, lane = tid & 63, wv = tid >> 6;
  int wm = wv >> 2, wn = wv & 3;
  int NT = Kd >> 6;
  int P = NT * 2;

  int P16 = wv * 64 + lane;
  int blk = P16 >> 3, up = P16 & 7;
  int uu = up ^ (blk & 7);
  int r0 = blk * 2 + (uu >> 2), cg0 = uu & 3;
  const u16* srcA = A + (size_t)(m0 + r0) * lda + cg0 * 8;
  const u16* srcB = Bt + (size_t)(n0 + r0) * Kd + cg0 * 8;
  size_t rsB = (size_t)128 * Kd;

  int offB = swz16(wn * 64 + (lane & 15), lane >> 4) * 8;
  int offA = swz16(wm * 64 + (lane & 15), lane >> 4) * 8;
  u16* ldsw = &lds[wv * 512];

  f32x4 acc[4][4] = {};
  B8 aR[4], bR[4];

  auto stage = [&](int q, int bB, int aB) {
    const u16* spB = srcB + q * 32;
    gll16(spB, ldsw + bB);
    gll16(spB + rsB, ldsw + bB + 4096);
    gll16(srcA + q * 32, ldsw + aB);
  };

  stage(0, 0, 24576);
  stage(1, 8192, 28672);
  asm volatile("s_waitcnt vmcnt(3)" ::: "memory");
  asm volatile("s_barrier" ::: "memory");

  int rB = 0, rA = 24576;
  int tB = 16384, tA = 32768;
  for (int p = 0; p < P; ++p) {
#pragma unroll
    for (int f = 0; f < 4; ++f) bR[f].u = *(const uint4*)&lds[rB + offB + f * 512];
#pragma unroll
    for (int f = 0; f < 4; ++f) aR[f].u = *(const uint4*)&lds[rA + offA + f * 512];
    if (p + 2 < P) stage(p + 2, tB, tA);
    asm volatile("s_barrier" ::: "memory");
    asm volatile("s_waitcnt lgkmcnt(0)" ::: "memory");
    __builtin_amdgcn_s_setprio(1);
#pragma unroll
    for (int nf = 0; nf < 4; ++nf)
#pragma unroll
      for (int mf = 0; mf < 4; ++mf)
        acc[mf][nf] = __builtin_amdgcn_mfma_f32_16x16x32_bf16(aR[mf].v, bR[nf].v, acc[mf][nf], 0, 0, 0);
    __builtin_amdgcn_s_setprio(0);
    if (p < P - 2) asm volatile("s_waitcnt vmcnt(3)" ::: "memory");
    else if (p == P - 2) asm volatile("s_waitcnt vmcnt(0)" ::: "memory");
    asm volatile("s_barrier" ::: "memory");
    tB = rB; tA = rA;
    rB = (rB == 16384) ? 0 : rB + 8192;
    rA = (rA == 32768) ? 24576 : rA + 4096;
  }

  if (EPI == 3) {
#pragma unroll
    for (int mf = 0; mf < 4; ++mf) {
      int rowb = m0 + wm * 64 + mf * 16 + (lane >> 4) * 4;
      int bb = rowb >> 10, kk2 = rowb & 1023;
      int w = kk2 & 127;
      int kk2p = (kk2 & ~127) | (((((w >> 5) & 3) << 2) + ((w >> 2) & 3)) << 3) | (((w >> 4) & 1) << 2);
#pragma unroll
      for (int nf = 0; nf < 4; ++nf) {
        int col = n0 + wn * 64 + nf * 16 + (lane & 15);
        if (col >= 4096) {
          int hh = (col - 4096) >> 7, dd = (col - 4096) & 127;
          ushort4 pk;
          pk.x = f2b(acc[mf][nf][0]); pk.y = f2b(acc[mf][nf][1]);
          pk.z = f2b(acc[mf][nf][2]); pk.w = f2b(acc[mf][nf][3]);
          *(ushort4*)&vTout[(((size_t)bb * 16 + hh) * 128 + dd) * 1024 + kk2p] = pk;
        } else {
#pragma unroll
          for (int rr = 0; rr < 4; ++rr)
            Cb[(size_t)(rowb + rr) * N + col] = f2b(acc[mf][nf][rr]);
        }
      }
    }
    return;
  }

#pragma unroll
  for (int mf = 0; mf < 4; ++mf) {
#pragma unroll
    for (int rr = 0; rr < 4; ++rr) {
      int row = m0 + wm * 64 + mf * 16 + (lane >> 4) * 4 + rr;
#pragma unroll
      for (int nf = 0; nf < 4; ++nf) {
        int col = n0 + wn * 64 + nf * 16 + (lane & 15);
        float v = acc[mf][nf][rr];
        if (EPI == 0) {
          Cb[(size_t)row * N + col] = f2b(v);
        } else if (EPI == 1) {
          int b = row >> 10;
          Cf[(size_t)row * Hh + col] = hid[((size_t)b * Ss + idx[row]) * Hh + col] + v;
        } else {
          int b = row >> 10;
          Cf[((size_t)b * Ss + idx[row]) * Hh + col] = hs2[(size_t)row * Hh + col] + v * scalev[b];
        }
      }
    }
  }
}

// ---------------- RoPE, 4 pairs/thread, vectorized (Q,K only) ----------------
__global__ __launch_bounds__(256) void rope_qk(u16* __restrict__ qkv,
                                               const int* __restrict__ posg) {
  int gid = blockIdx.x * 256 + threadIdx.x;
  int i4 = (gid & 15) << 2;
  int h = (gid >> 4) & 15;
  int t = gid >> 8;
  float p = (float)posg[t];
  size_t base = (size_t)t * 6144 + h * DHh + i4;
  u16* Q = qkv;
  u16* Kq = qkv + 2048;
  ushort4 q1 = *(ushort4*)&Q[base], q2 = *(ushort4*)&Q[base + 64];
  ushort4 k1 = *(ushort4*)&Kq[base], k2 = *(ushort4*)&Kq[base + 64];
  u16* q1p = (u16*)&q1; u16* q2p = (u16*)&q2;
  u16* k1p = (u16*)&k1; u16* k2p = (u16*)&k2;
#pragma unroll
  for (int j = 0; j < 4; ++j) {
    int i = i4 + j;
    float inv = exp2f(-(float)i * (13.287712379549449f / 64.0f));
    float sv, cv;
    __sincosf(p * inv, &sv, &cv);
    float a1 = b2f(q1p[j]), a2 = b2f(q2p[j]);
    q1p[j] = f2b(a1 * cv - a2 * sv);
    q2p[j] = f2b(a2 * cv + a1 * sv);
    float c1 = b2f(k1p[j]), c2 = b2f(k2p[j]);
    k1p[j] = f2b(c1 * cv - c2 * sv);
    k2p[j] = f2b(c2 * cv + c1 * sv);
  }
  *(ushort4*)&Q[base] = q1; *(ushort4*)&Q[base + 64] = q2;
  *(ushort4*)&Kq[base] = k1; *(ushort4*)&Kq[base + 64] = k2;
}

// ---------------- flash attention: KVBLK=128, register-P, split K/V waits, long-first ----------------
__global__ __launch_bounds__(256) void attn_k(const u16* __restrict__ QKV,
                                              const u16* __restrict__ vT,
                                              u16* __restrict__ O) {
  int qb = 15 - (int)blockIdx.x;  // long blocks (many tiles) dispatch first
  int head = blockIdx.y;
  int b = head >> 4, h = head & 15;
  int tid = threadIdx.x, lane = tid & 63, wv = tid >> 6;
  int l15 = lane & 15, lq = lane >> 4, l7 = lane & 7;
  __shared__ __align__(16) u16 KsA[16384];
  __shared__ __align__(16) u16 VtA[16384];

  int rr0 = tid >> 4;
  int u0 = tid & 15;
  size_t koff0 = (size_t)rr0 * 6144 + ((u0 ^ (rr0 & 7)) * 8);
  size_t voff0 = (size_t)rr0 * 1024 + ((u0 ^ (rr0 & 7)) * 8);
  char* dK = (char*)KsA + wv * 1024;
  char* dV = (char*)VtA + wv * 1024;

  int q0 = qb * 64 + wv * 16;
  int tokQ = b * KS + q0;
  B8 qf[4];
  const u16* qp = QKV + (size_t)(tokQ + l15) * 6144 + h * DHh;
#pragma unroll
  for (int c = 0; c < 4; ++c) qf[c].u = *(const uint4*)(qp + c * 32 + lq * 8);
  float m_run = -1e30f, l_run = 0.0f;
  f32x4 oacc[8] = {};
  int qi = q0 + l15;

  int nt = (qb >> 1) + 1;
  for (int t = 0; t < nt; ++t) {
    int ks = t * 128;
    bool maskTile = (t == nt - 1);
    __syncthreads();
    const u16* kp = QKV + (size_t)(b * KS + ks) * 6144 + 2048 + h * DHh + koff0;
    const u16* vp = vT + (size_t)head * 131072 + ks + voff0;
#pragma unroll
    for (int i = 0; i < 8; ++i) gll16(kp + (size_t)i * 98304, dK + i * 4096);
#pragma unroll
    for (int i = 0; i < 8; ++i) gll16(vp + i * 16384, dV + i * 4096);
    asm volatile("s_waitcnt vmcnt(8)" ::: "memory");
    __syncthreads();
    f32x4 st[8] = {};
#pragma unroll
    for (int c = 0; c < 4; ++c) {
#pragma unroll
      for (int kt = 0; kt < 8; ++kt) {
        B8 kf;
        kf.u = *(const uint4*)&KsA[(kt * 16 + l15) * 128 + (((c * 4 + lq) ^ l7) * 8)];
        st[kt] = __builtin_amdgcn_mfma_f32_16x16x32_bf16(kf.v, qf[c].v, st[kt], 0, 0, 0);
      }
    }
    float pmax = -INFINITY;
    if (maskTile) {
#pragma unroll
      for (int kt = 0; kt < 8; ++kt)
#pragma unroll
        for (int r = 0; r < 4; ++r) {
          int ki = ks + kt * 16 + lq * 4 + r;
          float v = st[kt][r] * 0.088388347648318447f;
          v = (ki <= qi) ? v : -INFINITY;
          st[kt][r] = v;
          pmax = fmaxf(pmax, v);
        }
    } else {
#pragma unroll
      for (int kt = 0; kt < 8; ++kt)
#pragma unroll
        for (int r = 0; r < 4; ++r) {
          float v = st[kt][r] * 0.088388347648318447f;
          st[kt][r] = v;
          pmax = fmaxf(pmax, v);
        }
    }
    pmax = fmaxf(pmax, __shfl_xor(pmax, 16));
    pmax = fmaxf(pmax, __shfl_xor(pmax, 32));
    float m_new = fmaxf(m_run, pmax);
    float alpha = __expf(m_run - m_new);
    float psum = 0.0f;
#pragma unroll
    for (int kt = 0; kt < 8; ++kt)
#pragma unroll
      for (int r = 0; r < 4; ++r) {
        float pv = __expf(st[kt][r] - m_new);
        st[kt][r] = pv;
        psum += pv;
      }
    psum += __shfl_xor(psum, 16);
    psum += __shfl_xor(psum, 32);
    l_run = l_run * alpha + psum;
    m_run = m_new;
    asm volatile("s_waitcnt vmcnt(0)" ::: "memory");
    __syncthreads();
    B8 pf[4];
#pragma unroll
    for (int kslot = 0; kslot < 4; ++kslot)
#pragma unroll
      for (int j = 0; j < 4; ++j) {
        pf[kslot].s[j] = f2b(st[2 * kslot][j]);
        pf[kslot].s[4 + j] = f2b(st[2 * kslot + 1][j]);
      }
    float al0 = __shfl(alpha, lq * 4 + 0);
    float al1 = __shfl(alpha, lq * 4 + 1);
    float al2 = __shfl(alpha, lq * 4 + 2);
    float al3 = __shfl(alpha, lq * 4 + 3);
#pragma unroll
    for (int dt = 0; dt < 8; ++dt) {
      oacc[dt][0] *= al0; oacc[dt][1] *= al1;
      oacc[dt][2] *= al2; oacc[dt][3] *= al3;
    }
#pragma unroll
    for (int dt = 0; dt < 8; ++dt) {
      int d = dt * 16 + l15;
#pragma unroll
      for (int kslot = 0; kslot < 4; ++kslot) {
        B8 vf;
        vf.u = *(const uint4*)&VtA[d * 128 + (((kslot * 4 + lq) ^ l7) * 8)];
        oacc[dt] = __builtin_amdgcn_mfma_f32_16x16x32_bf16(pf[kslot].v, vf.v, oacc[dt], 0, 0, 0);
      }
    }
  }
  float linv = 1.0f / l_run;
  float li[4];
#pragma unroll
  for (int r = 0; r < 4; ++r) li[r] = __shfl(linv, lq * 4 + r);
#pragma unroll
  for (int r = 0; r < 4; ++r) {
    int tok = tokQ + lq * 4 + r;
    u16* op = O + (size_t)tok * Hh + h * DHh;
#pragma unroll
    for (int dt = 0; dt < 8; ++dt) op[dt * 16 + l15] = f2b(oacc[dt][r] * li[r]);
  }
}

extern "C" void kernel_launch(void* const* d_in, const int* in_sizes, int n_in,
                              void* d_out, int out_size, void* d_ws, size_t ws_size,
                              hipStream_t stream) {
  (void)in_sizes; (void)n_in; (void)out_size; (void)ws_size;
  const float* hid = (const float*)d_in[0];
  const int* posids = (const int*)d_in[1];
  const void* mask = d_in[2];
  const float* scores = (const float*)d_in[3];
  const float* Wq = (const float*)d_in[5];
  const float* Wk = (const float*)d_in[6];
  const float* Wv = (const float*)d_in[7];
  const float* Wo = (const float*)d_in[8];
  const float* Wg = (const float*)d_in[9];
  const float* Wu = (const float*)d_in[10];
  const float* Wd = (const float*)d_in[11];
  const float* ln1 = (const float*)d_in[12];
  const float* ln2 = (const float*)d_in[13];
  float* out = (float*)d_out;
  char* ws = (char*)d_ws;

  u16* WqkvT = (u16*)(ws + 0);
  u16* WoT   = (u16*)(ws + 25165824);
  u16* WguT  = (u16*)(ws + 33554432);
  u16* WdT   = (u16*)(ws + 100663296);
  int* idx   = (int*)(ws + 134217728);
  int* posg  = (int*)(ws + 134217728 + 16384);
  float* scalev = (float*)(ws + 134217728 + 32768);
  char* R = ws + 134283264;
  u16* hsn    = (u16*)(R);
  u16* qkv    = (u16*)(R + 16777216);
  u16* attn_o = (u16*)(R + 67108864);
  u16* vT     = (u16*)(R + 88080384);
  u16* gu2    = (u16*)(R);
  float* hs2  = (float*)(ws + 268500992);
  u16* mnorm  = (u16*)(ws + 302055424);

  copy_hid<<<2048, 256, 0, stream>>>((const uint4*)hid, (uint4*)out);

  topk_prep<<<Bb, 256, 0, stream>>>(mask, posids, scores, idx, posg, scalev);

  transpose_w<0><<<dim3(64, 32), 256, 0, stream>>>(Wq, WqkvT, 2048, 2048);
  transpose_w<0><<<dim3(64, 32), 256, 0, stream>>>(Wk, WqkvT + 2048 * 2048, 2048, 2048);
  transpose_w<0><<<dim3(64, 32), 256, 0, stream>>>(Wv, WqkvT + 4096 * 2048, 2048, 2048);
  transpose_w<0><<<dim3(64, 32), 256, 0, stream>>>(Wo, WoT, 2048, 2048);
  transpose_w<1><<<dim3(256, 32), 256, 0, stream>>>(Wg, WguT, 2048, 8192);
  transpose_w<2><<<dim3(256, 32), 256, 0, stream>>>(Wu, WguT, 2048, 8192);
  transpose_w<0><<<dim3(64, 128), 256, 0, stream>>>(Wd, WdT, 8192, 2048);

  rmsnorm_k<1><<<NTOK, 256, 0, stream>>>(hid, idx, ln1, hsn);

  gemm128<3><<<768, 512, 0, stream>>>(hsn, WqkvT, 6144, 2048, 2048, 32, 3, 0, qkv,
                                      nullptr, nullptr, nullptr, nullptr, nullptr, vT);

  rope_qk<<<4096, 256, 0, stream>>>(qkv, posg);

  attn_k<<<dim3(16, 64), 256, 0, stream>>>(qkv, vT, attn_o);

  gemm128<1><<<256, 512, 0, stream>>>(attn_o, WoT, 2048, 2048, 2048, 32, 1, 1, nullptr,
                                      hid, idx, nullptr, nullptr, hs2, nullptr);

  rmsnorm_k<0><<<NTOK, 256, 0, stream>>>(hs2, nullptr, ln2, mnorm);

  gemm256<4><<<1024, 512, 0, stream>>>(mnorm, WguT, 16384, 2048, 2048, 16, 8, 0, gu2,
                                       nullptr, nullptr, nullptr, nullptr, nullptr);

  gemm128<2><<<256, 512, 0, stream>>>(gu2, WdT, 2048, 8192, 8192, 32, 1, 1, nullptr,
                                      nullptr, idx, hs2, scalev, out, nullptr);
}

// Round 14
// 969.919 us; speedup vs baseline: 1.0253x; 1.0253x over previous
//
#include <hip/hip_runtime.h>
#include <hip/hip_bf16.h>
#include <stdint.h>

#define Bb 4
#define Ss 8192
#define Hh 2048
#define NHh 16
#define DHh 128
#define DFFf 8192
#define KS 1024
#define NTOK 4096

typedef unsigned short u16;
typedef __bf16 bf16x8 __attribute__((ext_vector_type(8)));
typedef float f32x4 __attribute__((ext_vector_type(4)));

union B8 { uint4 u; bf16x8 v; u16 s[8]; };

__device__ __forceinline__ float b2f(u16 x) { return __uint_as_float(((unsigned)x) << 16); }
__device__ __forceinline__ u16 f2b(float x) {
  __hip_bfloat16 h = __float2bfloat16(x);
  return *reinterpret_cast<u16*>(&h);
}

__device__ __forceinline__ void gll16(const void* g, void* l) {
  __builtin_amdgcn_global_load_lds((const __attribute__((address_space(1))) void*)g,
                                   (__attribute__((address_space(3))) void*)l, 16, 0, 0);
}

__device__ __forceinline__ int swz16(int r, int cg) {
  int u = ((r & 1) << 2) | cg;
  return ((r >> 1) << 3) | (u ^ ((r >> 1) & 7));
}

// ---------------- top-k index scan ----------------
__global__ void topk_prep(const void* maskp, const int* __restrict__ posids,
                          const float* __restrict__ scores,
                          int* __restrict__ idx, int* __restrict__ posg,
                          float* __restrict__ scalev) {
  int b = blockIdx.x;
  int tid = threadIdx.x, lane = tid & 63, wv = tid >> 6;
  __shared__ int wsum[4];
  __shared__ int base;
  __shared__ int mode;
  __shared__ int detCnt;
  if (tid == 0) { base = 0; detCnt = 0; }
  __syncthreads();
  {
    const unsigned char* mb = (const unsigned char*)maskp;
    int c = 0;
    for (int s = tid; s < 8192; s += 256) c += (mb[s] != 0);
    atomicAdd(&detCnt, c);
  }
  __syncthreads();
  if (tid == 0) mode = (detCnt == KS) ? 1 : 0;
  __syncthreads();
  const unsigned char* mb = (const unsigned char*)maskp;
  const int* mi = (const int*)maskp;
  for (int s0 = 0; s0 < Ss; s0 += 256) {
    int s = s0 + tid;
    int pred = mode ? (mb[(size_t)b * Ss + s] != 0) : (mi[(size_t)b * Ss + s] != 0);
    unsigned long long bal = __ballot(pred);
    int lp = __popcll(bal & ((1ull << lane) - 1ull));
    int wtot = __popcll(bal);
    if (lane == 0) wsum[wv] = wtot;
    __syncthreads();
    int woff = 0;
    for (int w = 0; w < wv; ++w) woff += wsum[w];
    int tot = wsum[0] + wsum[1] + wsum[2] + wsum[3];
    int p = base + woff + lp;
    if (pred && p < KS) {
      idx[b * KS + p] = s;
      posg[b * KS + p] = posids[(size_t)b * Ss + s];
    }
    __syncthreads();
    if (tid == 0) base += tot;
    __syncthreads();
  }
  if (b == 0 && tid < Bb) scalev[tid] = 0.5f * 1.0f + (scores[tid] - 0.5f) * 1.0f;
}

// ---------------- fused 4x square weight transpose (2048x2048 each) ----------------
__global__ __launch_bounds__(256) void transpose_w4(
    const float* __restrict__ s0, const float* __restrict__ s1,
    const float* __restrict__ s2, const float* __restrict__ s3,
    u16* __restrict__ d0, u16* __restrict__ d1, u16* __restrict__ d2, u16* __restrict__ d3) {
  const float* srcs[4] = {s0, s1, s2, s3};
  u16* dsts[4] = {d0, d1, d2, d3};
  const float* in = srcs[blockIdx.z];
  u16* out = dsts[blockIdx.z];
  __shared__ float tile[64][33];
  int t = threadIdx.x;
  int c0 = blockIdx.x * 32, r0 = blockIdx.y * 64;
  int tx = t & 31, ty = t >> 5;
#pragma unroll
  for (int j = 0; j < 8; ++j)
    tile[j * 8 + ty][tx] = in[(size_t)(r0 + j * 8 + ty) * 2048 + c0 + tx];
  __syncthreads();
  int c = t >> 3, g = t & 7;
  B8 pk;
#pragma unroll
  for (int k = 0; k < 8; ++k) pk.s[k] = f2b(tile[g * 8 + k][c]);
  *(uint4*)&out[(size_t)(c0 + c) * 2048 + r0 + g * 8] = pk.u;
}

// ---------------- fused gate+up transpose (interleaved 64-row blocks) ----------------
__global__ __launch_bounds__(256) void transpose_gu(const float* __restrict__ gsrc,
                                                    const float* __restrict__ usrc,
                                                    u16* __restrict__ out) {
  int z = blockIdx.z;  // 0 = gate, 1 = up
  const float* in = z ? usrc : gsrc;
  __shared__ float tile[64][33];
  int t = threadIdx.x;
  int c0 = blockIdx.x * 32, r0 = blockIdx.y * 64;
  int tx = t & 31, ty = t >> 5;
#pragma unroll
  for (int j = 0; j < 8; ++j)
    tile[j * 8 + ty][tx] = in[(size_t)(r0 + j * 8 + ty) * 8192 + c0 + tx];
  __syncthreads();
  int c = t >> 3, g = t & 7;
  int cc = c0 + c;
  size_t row = (size_t)((cc >> 5) << 6) + (cc & 31) + (z ? 32 : 0);
  B8 pk;
#pragma unroll
  for (int k = 0; k < 8; ++k) pk.s[k] = f2b(tile[g * 8 + k][c]);
  *(uint4*)&out[row * 2048 + r0 + g * 8] = pk.u;
}

// ---------------- Wd transpose (8192x2048 -> [2048][8192]) ----------------
__global__ __launch_bounds__(256) void transpose_wd(const float* __restrict__ in,
                                                    u16* __restrict__ out) {
  __shared__ float tile[64][33];
  int t = threadIdx.x;
  int c0 = blockIdx.x * 32, r0 = blockIdx.y * 64;
  int tx = t & 31, ty = t >> 5;
#pragma unroll
  for (int j = 0; j < 8; ++j)
    tile[j * 8 + ty][tx] = in[(size_t)(r0 + j * 8 + ty) * 2048 + c0 + tx];
  __syncthreads();
  int c = t >> 3, g = t & 7;
  B8 pk;
#pragma unroll
  for (int k = 0; k < 8; ++k) pk.s[k] = f2b(tile[g * 8 + k][c]);
  *(uint4*)&out[(size_t)(c0 + c) * 8192 + r0 + g * 8] = pk.u;
}

// ---------------- RMSNorm ----------------
template <int GATHER>
__global__ __launch_bounds__(256) void rmsnorm_k(const float* __restrict__ src0,
                                                 const int* __restrict__ idx,
                                                 const float* __restrict__ w,
                                                 u16* __restrict__ out) {
  int t = blockIdx.x;
  const float* src;
  if (GATHER) { int b = t >> 10; src = src0 + ((size_t)b * Ss + idx[t]) * Hh; }
  else src = src0 + (size_t)t * Hh;
  int tid = threadIdx.x, lane = tid & 63, wv = tid >> 6;
  float4 x0 = *(const float4*)(src + tid * 8);
  float4 x1 = *(const float4*)(src + tid * 8 + 4);
  float ss = x0.x * x0.x + x0.y * x0.y + x0.z * x0.z + x0.w * x0.w +
             x1.x * x1.x + x1.y * x1.y + x1.z * x1.z + x1.w * x1.w;
  for (int o = 32; o; o >>= 1) ss += __shfl_down(ss, o);
  __shared__ float wred[4];
  if (lane == 0) wred[wv] = ss;
  __syncthreads();
  float tot = wred[0] + wred[1] + wred[2] + wred[3];
  float r = rsqrtf(tot * (1.0f / Hh) + 1e-5f);
  const float* wp = w + tid * 8;
  u16* op = out + (size_t)t * Hh + tid * 8;
  float xs[8] = {x0.x, x0.y, x0.z, x0.w, x1.x, x1.y, x1.z, x1.w};
#pragma unroll
  for (int j = 0; j < 8; ++j) op[j] = f2b(xs[j] * r * wp[j]);
}

// ---------------- 256x256 8-phase bf16 GEMM, pair-unrolled (frozen K-loop) ----------------
template <int EPI>
__global__ __launch_bounds__(512, 2) void gemm256(
    const u16* __restrict__ A, const u16* __restrict__ Bt,
    int N, int Kd, int lda, int gm, int gw, int nb,
    u16* __restrict__ Cb,
    const float* __restrict__ hid, const int* __restrict__ idx,
    const float* __restrict__ hs2, const float* __restrict__ scalev,
    float* __restrict__ Cf) {
  __shared__ u16 lds[65536];
  int bid = blockIdx.x;
  int xcd = bid & 7;
  int i2 = bid >> 3;
  int bm = i2 / gw;
  int bn = xcd * gw + i2 % gw + nb;
  int m0 = bm * 256, n0 = bn * 256;
  int tid = threadIdx.x, lane = tid & 63, wv = tid >> 6;
  int wm = wv >> 2, wn = wv & 3;
  int NT = Kd >> 6;

  int P16 = wv * 64 + lane;
  int blk = P16 >> 3, up = P16 & 7;
  int uu = up ^ (blk & 7);
  int r0 = blk * 2 + (uu >> 2), cg0 = uu & 3;
  const u16* srcA = A + (size_t)(m0 + r0) * lda + cg0 * 8;
  const u16* srcB = Bt + (size_t)(n0 + r0) * Kd + cg0 * 8;
  size_t rsA = (size_t)128 * lda, rsB = (size_t)128 * Kd;

  int offA = swz16(wm * 128 + (lane & 15), lane >> 4) * 8;
  int offB = 32768 + swz16(wn * 64 + (lane & 15), lane >> 4) * 8;
  u16* ldsw = &lds[wv * 512];

  f32x4 acc[8][4] = {};
  B8 aR[4], bR[4];

  gll16(srcB,      ldsw + 32768); gll16(srcB + rsB,      ldsw + 36864);
  gll16(srcA,      ldsw +     0); gll16(srcA + rsA,      ldsw +  4096);
  gll16(srcB + 32, ldsw + 40960); gll16(srcB + 32 + rsB, ldsw + 45056);
  gll16(srcA + 32, ldsw +  8192); gll16(srcA + 32 + rsA, ldsw + 12288);
  gll16(srcB + 64, ldsw + 49152); gll16(srcB + 64 + rsB, ldsw + 53248);
  gll16(srcA + 64, ldsw + 16384); gll16(srcA + 64 + rsA, ldsw + 20480);
  gll16(srcB + 96, ldsw + 57344); gll16(srcB + 96 + rsB, ldsw + 61440);
  asm volatile("s_waitcnt vmcnt(6)" ::: "memory");
  asm volatile("s_barrier" ::: "memory");

  const u16* stA = srcA + 64;
  const u16* stB = srcB + 64;

  auto phase = [&](int abase, int bbase, int mh) {
    if (mh == 0) {
#pragma unroll
      for (int nf = 0; nf < 4; ++nf) bR[nf].u = *(const uint4*)&lds[offB + bbase + nf * 512];
    }
#pragma unroll
    for (int i3 = 0; i3 < 4; ++i3)
      aR[i3].u = *(const uint4*)&lds[offA + abase + (i3 + 4 * mh) * 512];
  };
  auto mfma16 = [&](int mh) {
    asm volatile("s_barrier" ::: "memory");
    asm volatile("s_waitcnt lgkmcnt(0)" ::: "memory");
    __builtin_amdgcn_s_setprio(1);
#pragma unroll
    for (int nf = 0; nf < 4; ++nf)
#pragma unroll
      for (int i3 = 0; i3 < 4; ++i3)
        acc[mh * 4 + i3][nf] =
            __builtin_amdgcn_mfma_f32_16x16x32_bf16(aR[i3].v, bR[nf].v, acc[mh * 4 + i3][nf], 0, 0, 0);
    __builtin_amdgcn_s_setprio(0);
  };

  for (int ktp = 0; ktp < NT; ktp += 2) {
    bool sAll = (ktp < NT - 2);
    phase(0, 0, 0);
    { gll16(stA + 32, ldsw + 24576); gll16(stA + 32 + rsA, ldsw + 28672); }
    mfma16(0);
    asm volatile("s_barrier" ::: "memory");
    phase(0, 0, 1);
    if (sAll) { gll16(stB + 64, ldsw + 32768); gll16(stB + 64 + rsB, ldsw + 36864); }
    mfma16(1);
    asm volatile("s_barrier" ::: "memory");
    phase(8192, 8192, 0);
    if (sAll) { gll16(stA + 64, ldsw + 0); gll16(stA + 64 + rsA, ldsw + 4096); }
    mfma16(0);
    asm volatile("s_barrier" ::: "memory");
    phase(8192, 8192, 1);
    if (sAll) { gll16(stB + 96, ldsw + 40960); gll16(stB + 96 + rsB, ldsw + 45056); }
    mfma16(1);
    if (sAll) asm volatile("s_waitcnt vmcnt(6)" ::: "memory");
    else asm volatile("s_waitcnt vmcnt(0)" ::: "memory");
    asm volatile("s_barrier" ::: "memory");
    phase(16384, 16384, 0);
    if (sAll) { gll16(stA + 96, ldsw + 8192); gll16(stA + 96 + rsA, ldsw + 12288); }
    mfma16(0);
    asm volatile("s_barrier" ::: "memory");
    phase(16384, 16384, 1);
    if (sAll) { gll16(stB + 128, ldsw + 49152); gll16(stB + 128 + rsB, ldsw + 53248); }
    mfma16(1);
    asm volatile("s_barrier" ::: "memory");
    phase(24576, 24576, 0);
    if (sAll) { gll16(stA + 128, ldsw + 16384); gll16(stA + 128 + rsA, ldsw + 20480); }
    mfma16(0);
    asm volatile("s_barrier" ::: "memory");
    phase(24576, 24576, 1);
    if (sAll) { gll16(stB + 160, ldsw + 57344); gll16(stB + 160 + rsB, ldsw + 61440); }
    mfma16(1);
    if (sAll) asm volatile("s_waitcnt vmcnt(6)" ::: "memory");
    asm volatile("s_barrier" ::: "memory");
    stA += 128; stB += 128;
  }

  if (EPI == 4) {
    int gcol0 = ((n0 + wn * 64) >> 1) + (lane & 15);
#pragma unroll
    for (int mf = 0; mf < 8; ++mf) {
#pragma unroll
      for (int rr = 0; rr < 4; ++rr) {
        int row = m0 + wm * 128 + mf * 16 + (lane >> 4) * 4 + rr;
#pragma unroll
        for (int nf = 0; nf < 2; ++nf) {
          float g = acc[mf][nf][rr];
          float u = acc[mf][nf + 2][rr];
          Cb[(size_t)row * 8192 + gcol0 + nf * 16] = f2b(g / (1.0f + __expf(-g)) * u);
        }
      }
    }
    return;
  }

#pragma unroll
  for (int mf = 0; mf < 8; ++mf) {
#pragma unroll
    for (int rr = 0; rr < 4; ++rr) {
      int row = m0 + wm * 128 + mf * 16 + (lane >> 4) * 4 + rr;
#pragma unroll
      for (int nf = 0; nf < 4; ++nf) {
        int col = n0 + wn * 64 + nf * 16 + (lane & 15);
        float v = acc[mf][nf][rr];
        if (EPI == 0) {
          Cb[(size_t)row * N + col] = f2b(v);
        } else if (EPI == 1) {
          int b = row >> 10;
          Cf[(size_t)row * Hh + col] = hid[((size_t)b * Ss + idx[row]) * Hh + col] + v;
        } else {
          int b = row >> 10;
          Cf[((size_t)b * Ss + idx[row]) * Hh + col] = hs2[(size_t)row * Hh + col] + v * scalev[b];
        }
      }
    }
  }
}

// ---------------- 128x256 bf16 GEMM, 3-slot/36KB, pipelined ----------------
template <int EPI>
__global__ __launch_bounds__(512, 4) void gemm128(
    const u16* __restrict__ A, const u16* __restrict__ Bt,
    int N, int Kd, int lda, int gm, int gw, int r2d,
    u16* __restrict__ Cb,
    const float* __restrict__ hid, const int* __restrict__ idx,
    const float* __restrict__ hs2, const float* __restrict__ scalev,
    float* __restrict__ Cf, u16* __restrict__ vTout) {
  __shared__ u16 lds[36864];
  int bid = blockIdx.x;
  int xcd = bid & 7;
  int i2 = bid >> 3;
  int bm, bn;
  if (r2d) {
    int xr = xcd >> 1, xc = xcd & 1;
    bm = xr * 8 + (i2 & 7);
    bn = xc * 4 + (i2 >> 3);
  } else {
    bm = i2 / gw;
    bn = xcd * gw + i2 % gw;
  }
  int m0 = bm * 128, n0 = bn * 256;
  int tid = threadIdx.x, lane = tid & 63, wv = tid >> 6;
  int wm = wv >> 2, wn = wv & 3;
  int NT = Kd >> 6;
  int P = NT * 2;

  int P16 = wv * 64 + lane;
  int blk = P16 >> 3, up = P16 & 7;
  int uu = up ^ (blk & 7);
  int r0 = blk * 2 + (uu >> 2), cg0 = uu & 3;
  const u16* srcA = A + (size_t)(m0 + r0) * lda + cg0 * 8;
  const u16* srcB = Bt + (size_t)(n0 + r0) * Kd + cg0 * 8;
  size_t rsB = (size_t)128 * Kd;

  int offB = swz16(wn * 64 + (lane & 15), lane >> 4) * 8;
  int offA = swz16(wm * 64 + (lane & 15), lane >> 4) * 8;
  u16* ldsw = &lds[wv * 512];

  f32x4 acc[4][4] = {};
  B8 aR[4], bR[4];

  auto stage = [&](int q, int bB, int aB) {
    const u16* spB = srcB + q * 32;
    gll16(spB, ldsw + bB);
    gll16(spB + rsB, ldsw + bB + 4096);
    gll16(srcA + q * 32, ldsw + aB);
  };

  stage(0, 0, 24576);
  stage(1, 8192, 28672);
  asm volatile("s_waitcnt vmcnt(3)" ::: "memory");
  asm volatile("s_barrier" ::: "memory");

  int rB = 0, rA = 24576;
  int tB = 16384, tA = 32768;
  for (int p = 0; p < P; ++p) {
#pragma unroll
    for (int f = 0; f < 4; ++f) bR[f].u = *(const uint4*)&lds[rB + offB + f * 512];
#pragma unroll
    for (int f = 0; f < 4; ++f) aR[f].u = *(const uint4*)&lds[rA + offA + f * 512];
    if (p + 2 < P) stage(p + 2, tB, tA);
    asm volatile("s_barrier" ::: "memory");
    asm volatile("s_waitcnt lgkmcnt(0)" ::: "memory");
    __builtin_amdgcn_s_setprio(1);
#pragma unroll
    for (int nf = 0; nf < 4; ++nf)
#pragma unroll
      for (int mf = 0; mf < 4; ++mf)
        acc[mf][nf] = __builtin_amdgcn_mfma_f32_16x16x32_bf16(aR[mf].v, bR[nf].v, acc[mf][nf], 0, 0, 0);
    __builtin_amdgcn_s_setprio(0);
    if (p < P - 2) asm volatile("s_waitcnt vmcnt(3)" ::: "memory");
    else if (p == P - 2) asm volatile("s_waitcnt vmcnt(0)" ::: "memory");
    asm volatile("s_barrier" ::: "memory");
    tB = rB; tA = rA;
    rB = (rB == 16384) ? 0 : rB + 8192;
    rA = (rA == 32768) ? 24576 : rA + 4096;
  }

  if (EPI == 3) {
#pragma unroll
    for (int mf = 0; mf < 4; ++mf) {
      int rowb = m0 + wm * 64 + mf * 16 + (lane >> 4) * 4;
      int bb = rowb >> 10, kk2 = rowb & 1023;
      int w = kk2 & 127;
      int kk2p = (kk2 & ~127) | (((((w >> 5) & 3) << 2) + ((w >> 2) & 3)) << 3) | (((w >> 4) & 1) << 2);
#pragma unroll
      for (int nf = 0; nf < 4; ++nf) {
        int col = n0 + wn * 64 + nf * 16 + (lane & 15);
        if (col >= 4096) {
          int hh = (col - 4096) >> 7, dd = (col - 4096) & 127;
          ushort4 pk;
          pk.x = f2b(acc[mf][nf][0]); pk.y = f2b(acc[mf][nf][1]);
          pk.z = f2b(acc[mf][nf][2]); pk.w = f2b(acc[mf][nf][3]);
          *(ushort4*)&vTout[(((size_t)bb * 16 + hh) * 128 + dd) * 1024 + kk2p] = pk;
        } else {
#pragma unroll
          for (int rr = 0; rr < 4; ++rr)
            Cb[(size_t)(rowb + rr) * N + col] = f2b(acc[mf][nf][rr]);
        }
      }
    }
    return;
  }

#pragma unroll
  for (int mf = 0; mf < 4; ++mf) {
#pragma unroll
    for (int rr = 0; rr < 4; ++rr) {
      int row = m0 + wm * 64 + mf * 16 + (lane >> 4) * 4 + rr;
#pragma unroll
      for (int nf = 0; nf < 4; ++nf) {
        int col = n0 + wn * 64 + nf * 16 + (lane & 15);
        float v = acc[mf][nf][rr];
        if (EPI == 0) {
          Cb[(size_t)row * N + col] = f2b(v);
        } else if (EPI == 1) {
          int b = row >> 10;
          Cf[(size_t)row * Hh + col] = hid[((size_t)b * Ss + idx[row]) * Hh + col] + v;
        } else {
          int b = row >> 10;
          Cf[((size_t)b * Ss + idx[row]) * Hh + col] = hs2[(size_t)row * Hh + col] + v * scalev[b];
        }
      }
    }
  }
}

// ---------------- RoPE, 4 pairs/thread, vectorized (Q,K only) ----------------
__global__ __launch_bounds__(256) void rope_qk(u16* __restrict__ qkv,
                                               const int* __restrict__ posg) {
  int gid = blockIdx.x * 256 + threadIdx.x;
  int i4 = (gid & 15) << 2;
  int h = (gid >> 4) & 15;
  int t = gid >> 8;
  float p = (float)posg[t];
  size_t base = (size_t)t * 6144 + h * DHh + i4;
  u16* Q = qkv;
  u16* Kq = qkv + 2048;
  ushort4 q1 = *(ushort4*)&Q[base], q2 = *(ushort4*)&Q[base + 64];
  ushort4 k1 = *(ushort4*)&Kq[base], k2 = *(ushort4*)&Kq[base + 64];
  u16* q1p = (u16*)&q1; u16* q2p = (u16*)&q2;
  u16* k1p = (u16*)&k1; u16* k2p = (u16*)&k2;
#pragma unroll
  for (int j = 0; j < 4; ++j) {
    int i = i4 + j;
    float inv = exp2f(-(float)i * (13.287712379549449f / 64.0f));
    float sv, cv;
    __sincosf(p * inv, &sv, &cv);
    float a1 = b2f(q1p[j]), a2 = b2f(q2p[j]);
    q1p[j] = f2b(a1 * cv - a2 * sv);
    q2p[j] = f2b(a2 * cv + a1 * sv);
    float c1 = b2f(k1p[j]), c2 = b2f(k2p[j]);
    k1p[j] = f2b(c1 * cv - c2 * sv);
    k2p[j] = f2b(c2 * cv + c1 * sv);
  }
  *(ushort4*)&Q[base] = q1; *(ushort4*)&Q[base + 64] = q2;
  *(ushort4*)&Kq[base] = k1; *(ushort4*)&Kq[base + 64] = k2;
}

// ---------------- flash attention: KVBLK=128, register-P, split K/V waits, long-first ----------------
__global__ __launch_bounds__(256) void attn_k(const u16* __restrict__ QKV,
                                              const u16* __restrict__ vT,
                                              u16* __restrict__ O) {
  int qb = 15 - (int)blockIdx.x;
  int head = blockIdx.y;
  int b = head >> 4, h = head & 15;
  int tid = threadIdx.x, lane = tid & 63, wv = tid >> 6;
  int l15 = lane & 15, lq = lane >> 4, l7 = lane & 7;
  __shared__ __align__(16) u16 KsA[16384];
  __shared__ __align__(16) u16 VtA[16384];

  int rr0 = tid >> 4;
  int u0 = tid & 15;
  size_t koff0 = (size_t)rr0 * 6144 + ((u0 ^ (rr0 & 7)) * 8);
  size_t voff0 = (size_t)rr0 * 1024 + ((u0 ^ (rr0 & 7)) * 8);
  char* dK = (char*)KsA + wv * 1024;
  char* dV = (char*)VtA + wv * 1024;

  int q0 = qb * 64 + wv * 16;
  int tokQ = b * KS + q0;
  B8 qf[4];
  const u16* qp = QKV + (size_t)(tokQ + l15) * 6144 + h * DHh;
#pragma unroll
  for (int c = 0; c < 4; ++c) qf[c].u = *(const uint4*)(qp + c * 32 + lq * 8);
  float m_run = -1e30f, l_run = 0.0f;
  f32x4 oacc[8] = {};
  int qi = q0 + l15;

  int nt = (qb >> 1) + 1;
  for (int t = 0; t < nt; ++t) {
    int ks = t * 128;
    bool maskTile = (t == nt - 1);
    __syncthreads();
    const u16* kp = QKV + (size_t)(b * KS + ks) * 6144 + 2048 + h * DHh + koff0;
    const u16* vp = vT + (size_t)head * 131072 + ks + voff0;
#pragma unroll
    for (int i = 0; i < 8; ++i) gll16(kp + (size_t)i * 98304, dK + i * 4096);
#pragma unroll
    for (int i = 0; i < 8; ++i) gll16(vp + i * 16384, dV + i * 4096);
    asm volatile("s_waitcnt vmcnt(8)" ::: "memory");
    __syncthreads();
    f32x4 st[8] = {};
#pragma unroll
    for (int c = 0; c < 4; ++c) {
#pragma unroll
      for (int kt = 0; kt < 8; ++kt) {
        B8 kf;
        kf.u = *(const uint4*)&KsA[(kt * 16 + l15) * 128 + (((c * 4 + lq) ^ l7) * 8)];
        st[kt] = __builtin_amdgcn_mfma_f32_16x16x32_bf16(kf.v, qf[c].v, st[kt], 0, 0, 0);
      }
    }
    float pmax = -INFINITY;
    if (maskTile) {
#pragma unroll
      for (int kt = 0; kt < 8; ++kt)
#pragma unroll
        for (int r = 0; r < 4; ++r) {
          int ki = ks + kt * 16 + lq * 4 + r;
          float v = st[kt][r] * 0.088388347648318447f;
          v = (ki <= qi) ? v : -INFINITY;
          st[kt][r] = v;
          pmax = fmaxf(pmax, v);
        }
    } else {
#pragma unroll
      for (int kt = 0; kt < 8; ++kt)
#pragma unroll
        for (int r = 0; r < 4; ++r) {
          float v = st[kt][r] * 0.088388347648318447f;
          st[kt][r] = v;
          pmax = fmaxf(pmax, v);
        }
    }
    pmax = fmaxf(pmax, __shfl_xor(pmax, 16));
    pmax = fmaxf(pmax, __shfl_xor(pmax, 32));
    float m_new = fmaxf(m_run, pmax);
    float alpha = __expf(m_run - m_new);
    float psum = 0.0f;
#pragma unroll
    for (int kt = 0; kt < 8; ++kt)
#pragma unroll
      for (int r = 0; r < 4; ++r) {
        float pv = __expf(st[kt][r] - m_new);
        st[kt][r] = pv;
        psum += pv;
      }
    psum += __shfl_xor(psum, 16);
    psum += __shfl_xor(psum, 32);
    l_run = l_run * alpha + psum;
    m_run = m_new;
    asm volatile("s_waitcnt vmcnt(0)" ::: "memory");
    __syncthreads();
    B8 pf[4];
#pragma unroll
    for (int kslot = 0; kslot < 4; ++kslot)
#pragma unroll
      for (int j = 0; j < 4; ++j) {
        pf[kslot].s[j] = f2b(st[2 * kslot][j]);
        pf[kslot].s[4 + j] = f2b(st[2 * kslot + 1][j]);
      }
    float al0 = __shfl(alpha, lq * 4 + 0);
    float al1 = __shfl(alpha, lq * 4 + 1);
    float al2 = __shfl(alpha, lq * 4 + 2);
    float al3 = __shfl(alpha, lq * 4 + 3);
#pragma unroll
    for (int dt = 0; dt < 8; ++dt) {
      oacc[dt][0] *= al0; oacc[dt][1] *= al1;
      oacc[dt][2] *= al2; oacc[dt][3] *= al3;
    }
#pragma unroll
    for (int dt = 0; dt < 8; ++dt) {
      int d = dt * 16 + l15;
#pragma unroll
      for (int kslot = 0; kslot < 4; ++kslot) {
        B8 vf;
        vf.u = *(const uint4*)&VtA[d * 128 + (((kslot * 4 + lq) ^ l7) * 8)];
        oacc[dt] = __builtin_amdgcn_mfma_f32_16x16x32_bf16(pf[kslot].v, vf.v, oacc[dt], 0, 0, 0);
      }
    }
  }
  float linv = 1.0f / l_run;
  float li[4];
#pragma unroll
  for (int r = 0; r < 4; ++r) li[r] = __shfl(linv, lq * 4 + r);
#pragma unroll
  for (int r = 0; r < 4; ++r) {
    int tok = tokQ + lq * 4 + r;
    u16* op = O + (size_t)tok * Hh + h * DHh;
#pragma unroll
    for (int dt = 0; dt < 8; ++dt) op[dt * 16 + l15] = f2b(oacc[dt][r] * li[r]);
  }
}

extern "C" void kernel_launch(void* const* d_in, const int* in_sizes, int n_in,
                              void* d_out, int out_size, void* d_ws, size_t ws_size,
                              hipStream_t stream) {
  (void)in_sizes; (void)n_in; (void)out_size; (void)ws_size;
  const float* hid = (const float*)d_in[0];
  const int* posids = (const int*)d_in[1];
  const void* mask = d_in[2];
  const float* scores = (const float*)d_in[3];
  const float* Wq = (const float*)d_in[5];
  const float* Wk = (const float*)d_in[6];
  const float* Wv = (const float*)d_in[7];
  const float* Wo = (const float*)d_in[8];
  const float* Wg = (const float*)d_in[9];
  const float* Wu = (const float*)d_in[10];
  const float* Wd = (const float*)d_in[11];
  const float* ln1 = (const float*)d_in[12];
  const float* ln2 = (const float*)d_in[13];
  float* out = (float*)d_out;
  char* ws = (char*)d_ws;

  u16* WqkvT = (u16*)(ws + 0);
  u16* WoT   = (u16*)(ws + 25165824);
  u16* WguT  = (u16*)(ws + 33554432);
  u16* WdT   = (u16*)(ws + 100663296);
  int* idx   = (int*)(ws + 134217728);
  int* posg  = (int*)(ws + 134217728 + 16384);
  float* scalev = (float*)(ws + 134217728 + 32768);
  char* R = ws + 134283264;
  u16* hsn    = (u16*)(R);
  u16* qkv    = (u16*)(R + 16777216);
  u16* attn_o = (u16*)(R + 67108864);
  u16* vT     = (u16*)(R + 88080384);
  u16* gu2    = (u16*)(R);
  float* hs2  = (float*)(ws + 268500992);
  u16* mnorm  = (u16*)(ws + 302055424);

  hipMemcpyAsync(out, hid, (size_t)Bb * Ss * Hh * 4, hipMemcpyDeviceToDevice, stream);

  topk_prep<<<Bb, 256, 0, stream>>>(mask, posids, scores, idx, posg, scalev);

  transpose_w4<<<dim3(64, 32, 4), 256, 0, stream>>>(
      Wq, Wk, Wv, Wo, WqkvT, WqkvT + 2048 * 2048, WqkvT + 4096 * 2048, WoT);
  transpose_gu<<<dim3(256, 32, 2), 256, 0, stream>>>(Wg, Wu, WguT);
  transpose_wd<<<dim3(64, 128), 256, 0, stream>>>(Wd, WdT);

  rmsnorm_k<1><<<NTOK, 256, 0, stream>>>(hid, idx, ln1, hsn);

  gemm128<3><<<768, 512, 0, stream>>>(hsn, WqkvT, 6144, 2048, 2048, 32, 3, 0, qkv,
                                      nullptr, nullptr, nullptr, nullptr, nullptr, vT);

  rope_qk<<<4096, 256, 0, stream>>>(qkv, posg);

  attn_k<<<dim3(16, 64), 256, 0, stream>>>(qkv, vT, attn_o);

  gemm128<1><<<256, 512, 0, stream>>>(attn_o, WoT, 2048, 2048, 2048, 32, 1, 1, nullptr,
                                      hid, idx, nullptr, nullptr, hs2, nullptr);

  rmsnorm_k<0><<<NTOK, 256, 0, stream>>>(hs2, nullptr, ln2, mnorm);

  gemm256<4><<<1024, 512, 0, stream>>>(mnorm, WguT, 16384, 2048, 2048, 16, 8, 0, gu2,
                                       nullptr, nullptr, nullptr, nullptr, nullptr);

  gemm128<2><<<256, 512, 0, stream>>>(gu2, WdT, 2048, 8192, 8192, 32, 1, 1, nullptr,
                                      nullptr, idx, hs2, scalev, out, nullptr);
}